// Round 16
// baseline (1378.755 us; speedup 1.0000x reference)
//
#include <hip/hip_runtime.h>

// GNODecoder round 27 (resubmit; never ran -- broker timeout).
// r26 post-mortem: spill fix confirmed by counters (WRITE 975->50MB, hbm
// 2.21->0.22GB, VGPR 64->124) but fused only 825->770us and occupancy
// HALVED 43->22% (VGPR-bound waves). r24's lesson: +2.5GB traffic cost only
// +130us -> memory system mostly idle -> kernel is latency-bound with too
// few resident waves. All structures land 770-915us, all pipes <12% busy.
// r27: B-fragments (W1T/W2T, 24KB) read directly from GLOBAL wimg --
// L1-resident per CU -- with a re-packed layout so each B-load's 64 lanes
// read 1KB CONTIGUOUS (lane addr = nt*2048 + hi*1024 + c16*64 + g*16).
// Identical per-lane bytes -> bit-identical math. LDS 38.9->14.4KB, weight
// staging + its barrier gone. Occupancy 22 -> 40-50% predicted.
// Predicted: fused 770 -> 400-550us (null <=10% falsifies TLP theory ->
// pivot to gather-request reduction).

#define BLOCK 256

typedef _Float16 half8 __attribute__((ext_vector_type(8)));
typedef float f32x4 __attribute__((ext_vector_type(4)));

// LDS byte layout (fused kernel):
//   [0,    8192)  hbuf: per-wave 2 KB, [16 rows][8 chunks of 16B], chunk^=(row&7)
//   [8192, ... )  sacc: [QB][129] f32
// wimg GLOBAL layout (16B chunk units): chunk(n,ks) [n=nt*16+c16, k=ks*8+j]
//   W1 (nt<4):  unit = ((nt*2 + (ks>>2))*16 + c16)*4 + (ks&3)          [0,512)
//   W2 (nt<8):  unit = 512 + ((nt*2 + (ks>>2))*16 + c16)*4 + (ks&3)    [512,1536)
// B-load for lane (g,c16), tile-col nt, half hi: byte = base + nt*2048 +
//   hi*1024 + c16*64 + g*16  -> 64 lanes span 1KB contiguous (coalesced).

__device__ __forceinline__ float gelu_f(float x) {
    // jax.nn.gelu default (approximate=True, tanh form)
    float x3 = x * x * x;
    float t  = 0.7978845608028654f * fmaf(0.044715f, x3, x);
    float e  = __expf(2.0f * t);
    float r  = __builtin_amdgcn_rcpf(e + 1.0f);
    return 0.5f * x * (1.0f + (1.0f - 2.0f * r));
}

// ---------- sort machinery (proven) ----------

__global__ void hist_kernel(const int* __restrict__ dst, int* __restrict__ hist, int E) {
    int e = blockIdx.x * blockDim.x + threadIdx.x;
    if (e < E) atomicAdd(&hist[dst[e]], 1);
}

__global__ __launch_bounds__(1024) void scan_kernel(const int* __restrict__ hist,
                                                    int* __restrict__ start, int n) {
    __shared__ int wsum[16];
    __shared__ int woff[16];
    int tid = threadIdx.x;
    int lane = tid & 63, wid = tid >> 6;
    int carry = 0;  // meaningful on tid 0 only
    for (int base = 0; base < n; base += 1024) {
        int i = base + tid;
        int v = (i < n) ? hist[i] : 0;
        int incl = v;
#pragma unroll
        for (int off = 1; off < 64; off <<= 1) {
            int t = __shfl_up(incl, off, 64);
            if (lane >= off) incl += t;
        }
        if (lane == 63) wsum[wid] = incl;
        __syncthreads();
        if (tid == 0) {
            int acc = carry;
#pragma unroll
            for (int w = 0; w < 16; ++w) { woff[w] = acc; acc += wsum[w]; }
            carry = acc;
        }
        __syncthreads();
        if (i < n) start[i] = woff[wid] + incl - v;
        __syncthreads();
    }
    if (threadIdx.x == 0) start[n] = carry;
}

__global__ void scatter_kernel(const int* __restrict__ dst, const int* __restrict__ src,
                               const int* __restrict__ start, int* __restrict__ cursor,
                               int* __restrict__ dsts, int* __restrict__ srcs, int E) {
    int e = blockIdx.x * blockDim.x + threadIdx.x;
    if (e >= E) return;
    int d = dst[e];
    int pos = start[d] + atomicAdd(&cursor[d], 1);
    dsts[pos] = d;
    srcs[pos] = src[e];
}

// ---------- weight prep: f16 chunks, coalesced-global layout ----------

__global__ void wprep_kernel(const float* __restrict__ W1,
                             const float* __restrict__ W2,
                             uint4* __restrict__ img) {
    union { _Float16 h[8]; uint4 u; } cv;
    for (int task = threadIdx.x; task < 1536; task += 256) {
        bool isW2 = task >= 512;
        int id = isW2 ? task - 512 : task;
        int n = id >> 3, ks = id & 7;
        const float* W = isW2 ? W2 : W1;
        int N = isW2 ? 128 : 64;
#pragma unroll
        for (int j = 0; j < 8; ++j) cv.h[j] = (_Float16)W[(ks * 8 + j) * N + n];
        int nt = n >> 4, c16 = n & 15, g = ks & 3, hi = ks >> 2;
        int unit = (isW2 ? 512 : 0) + ((nt * 2 + hi) * 16 + c16) * 4 + g;
        img[unit] = cv.u;
    }
}

// ---------- fused: wave-private 16-edge tiles, weights via L1 ----------

template <int QB, bool FUSED_PROJ>
__global__ __launch_bounds__(BLOCK, 2) void fused_kernel(
    const float* __restrict__ rndata,   // [NL,128]
    const float* __restrict__ qpos,     // [NQ,3]
    const float* __restrict__ lpos,     // [NL,3]
    const int*   __restrict__ dsts,     // [E] sorted by dst
    const int*   __restrict__ srcs,     // [E]
    const int*   __restrict__ start,    // [NQ+1]
    const float* __restrict__ W0, const float* __restrict__ b0,
    const float* __restrict__ b1, const float* __restrict__ b2,
    const uint4* __restrict__ wimg,     // 24576 B packed W1T/W2T image
    const float* __restrict__ P0, const float* __restrict__ pb0,
    const float* __restrict__ P1, const float* __restrict__ pb1,
    float* __restrict__ agg,            // [NQ,128] mean (path A)
    float* __restrict__ out,            // [NQ,4]   (FUSED_PROJ)
    int nq)
{
    extern __shared__ char smemc[];
    float* sacc = (float*)(smemc + 8192);
    const int tid = threadIdx.x;

    for (int i = tid; i < QB * 129; i += BLOCK) sacc[i] = 0.f;

    const int q0   = blockIdx.x * QB;
    const int qend = min(q0 + QB, nq);
    const int e0 = start[q0], e1 = start[qend];
    const int ntl = (e1 - e0 + 15) >> 4;   // 16-edge tiles

    const int m   = tid & 63;
    const int wid = tid >> 6;
    const int c16 = m & 15;
    const int g   = m >> 4;                // 0..3 = k-group

    char* hb = smemc + wid * 2048;         // wave-private h1 buffer
    const int aoff0 = c16 * 128 + (((0 + g) ^ (c16 & 7)) * 16);  // A frag k=g*8..
    const int aoff1 = c16 * 128 + (((4 + g) ^ (c16 & 7)) * 16);  // A frag k=32+g*8..

    // coalesced B-load base: lanes (g,c16) -> c16*64 + g*16 (1KB/instr)
    const char* wimgc = (const char*)wimg + c16 * 64 + g * 16;

    // per-lane bias slices (hoisted; 12 loop-carried regs)
    float b1v[4], b2v[8];
#pragma unroll
    for (int nt = 0; nt < 4; ++nt) b1v[nt] = b1[nt * 16 + c16];
#pragma unroll
    for (int nt = 0; nt < 8; ++nt) b2v[nt] = b2[nt * 16 + c16];

    __syncthreads();  // sacc zeroed (only barrier before tail)

    for (int t = wid; t < ntl; t += 4) {
        const int eb = e0 + (t << 4);

        // ---- gather indices (issued first; all independent) ----
        const int  eA = eb + c16;
        const bool vA = eA < e1;
        const int  dA = vA ? dsts[eA] : q0;
        const int  sA = vA ? srcs[eA] : 0;

        int s_ep[4], soff[4];
        bool v_ep[4];
#pragma unroll
        for (int i = 0; i < 4; ++i) {
            int ee = eb + g * 4 + i;
            v_ep[i] = ee < e1;
            int d   = v_ep[i] ? dsts[ee] : q0;
            s_ep[i] = v_ep[i] ? srcs[ee] : 0;
            soff[i] = (d - q0) * 129 + c16;
        }

        float pin[6];
        {
            const float* pq = qpos + dA * 3;
            pin[0] = pq[0]; pin[1] = pq[1]; pin[2] = pq[2];
            const float* pl = lpos + sA * 3;
            pin[3] = pl[0]; pin[4] = pl[1]; pin[5] = pl[2];
        }

        // ---- L0: compute A-fragment directly (edge c16, cols g*8 sliced) ----
        float C0[16];
        {
            const float* b0p = b0 + g * 8;
            *(float4*)&C0[0]  = *(const float4*)(b0p);
            *(float4*)&C0[4]  = *(const float4*)(b0p + 4);
            *(float4*)&C0[8]  = *(const float4*)(b0p + 32);
            *(float4*)&C0[12] = *(const float4*)(b0p + 36);
        }
#pragma unroll
        for (int k = 0; k < 6; ++k) {
            const float a  = pin[k];
            const float* w = W0 + k * 64 + g * 8;   // L1-hot (1.5 KB total)
            float wv[16];
            *(float4*)&wv[0]  = *(const float4*)(w);
            *(float4*)&wv[4]  = *(const float4*)(w + 4);
            *(float4*)&wv[8]  = *(const float4*)(w + 32);
            *(float4*)&wv[12] = *(const float4*)(w + 36);
#pragma unroll
            for (int j = 0; j < 16; ++j) C0[j] = fmaf(a, wv[j], C0[j]);
        }
        union { _Float16 h[8]; half8 v; } u0, u1;
#pragma unroll
        for (int j = 0; j < 8; ++j) u0.h[j] = (_Float16)gelu_f(C0[j]);
#pragma unroll
        for (int j = 0; j < 8; ++j) u1.h[j] = (_Float16)gelu_f(C0[8 + j]);
        const half8 a0 = u0.v, a1 = u1.v;   // h0 A-fragments: no LDS round-trip

        // ---- GEMM2 interleaved with h1 transpose; B via L1 (coalesced) ----
#pragma unroll
        for (int nt = 0; nt < 4; ++nt) {
            half8 bb0 = *(const half8*)(wimgc + nt * 2048);
            half8 bb1 = *(const half8*)(wimgc + nt * 2048 + 1024);
            f32x4 acc = {b1v[nt], b1v[nt], b1v[nt], b1v[nt]};
            acc = __builtin_amdgcn_mfma_f32_16x16x32_f16(a0, bb0, acc, 0, 0, 0);
            acc = __builtin_amdgcn_mfma_f32_16x16x32_f16(a1, bb1, acc, 0, 0, 0);
#pragma unroll
            for (int i = 0; i < 4; ++i) {
                const int row  = g * 4 + i;
                const int colh = nt * 16 + c16;
                *(_Float16*)(hb + row * 128 + (((colh >> 3) ^ (row & 7)) * 16)
                             + (colh & 7) * 2) = (_Float16)gelu_f(acc[i]);
            }
        }
        // in-order DS per wave: reads below see the 16 writes above
        const half8 a2 = *(const half8*)(hb + aoff0);
        const half8 a3 = *(const half8*)(hb + aoff1);

        // ---- GEMM3 + epilogue, 2-deep rolling rndata buffer; B via L1 ----
        f32x4 rAv, rBv;
#pragma unroll
        for (int i = 0; i < 4; ++i)
            rAv[i] = rndata[(size_t)s_ep[i] * 128 + c16];      // nt=0 column
#pragma unroll
        for (int nt = 0; nt < 8; ++nt) {
            if (nt < 7) {        // issue nt+1 loads (hide under MFMAs)
                if (nt & 1) {
#pragma unroll
                    for (int i = 0; i < 4; ++i)
                        rAv[i] = rndata[(size_t)s_ep[i] * 128 + (nt + 1) * 16 + c16];
                } else {
#pragma unroll
                    for (int i = 0; i < 4; ++i)
                        rBv[i] = rndata[(size_t)s_ep[i] * 128 + (nt + 1) * 16 + c16];
                }
            }
            half8 bb0 = *(const half8*)(wimgc + 8192 + nt * 2048);
            half8 bb1 = *(const half8*)(wimgc + 8192 + nt * 2048 + 1024);
            f32x4 acc = {b2v[nt], b2v[nt], b2v[nt], b2v[nt]};
            acc = __builtin_amdgcn_mfma_f32_16x16x32_f16(a2, bb0, acc, 0, 0, 0);
            acc = __builtin_amdgcn_mfma_f32_16x16x32_f16(a3, bb1, acc, 0, 0, 0);
#pragma unroll
            for (int i = 0; i < 4; ++i) {
                float rc = (nt & 1) ? rBv[i] : rAv[i];
                if (v_ep[i]) atomicAdd(&sacc[soff[i] + nt * 16], acc[i] * rc);
            }
        }
    }
    __syncthreads();  // all waves' ds_adds visible

    if (!FUSED_PROJ) {
        for (int idx = tid; idx < QB * 128; idx += BLOCK) {
            int ql = idx >> 7, c = idx & 127;
            int q  = q0 + ql;
            if (q < qend) {
                float deg = (float)(start[q + 1] - start[q]);
                agg[(size_t)q * 128 + c] = sacc[ql * 129 + c] / fmaxf(deg, 1.f);
            }
        }
    } else {
        if (tid < QB) {
            int q = q0 + tid;
            if (q < nq) {
                float deg = (float)(start[q + 1] - start[q]);
                float inv = 1.0f / fmaxf(deg, 1.f);
                const float* aq = &sacc[tid * 129];
                float o0 = pb1[0], o1 = pb1[1], o2 = pb1[2], o3 = pb1[3];
#pragma unroll 1
                for (int jj = 0; jj < 256; jj += 8) {
                    float acc[8];
#pragma unroll
                    for (int u = 0; u < 8; ++u) acc[u] = pb0[jj + u];
#pragma unroll
                    for (int i = 0; i < 128; ++i) {
                        float av = aq[i] * inv;
#pragma unroll
                        for (int u = 0; u < 8; ++u)
                            acc[u] = fmaf(av, P0[i * 256 + jj + u], acc[u]);
                    }
#pragma unroll
                    for (int u = 0; u < 8; ++u) {
                        float h = gelu_f(acc[u]);
                        o0 = fmaf(h, P1[(jj + u) * 4 + 0], o0);
                        o1 = fmaf(h, P1[(jj + u) * 4 + 1], o1);
                        o2 = fmaf(h, P1[(jj + u) * 4 + 2], o2);
                        o3 = fmaf(h, P1[(jj + u) * 4 + 3], o3);
                    }
                }
                float4* o4 = (float4*)(out + (size_t)q * 4);
                *o4 = make_float4(o0, o1, o2, o3);
            }
        }
    }
}

// ---------- projection: plain r7/r9 kernel (proven ~270 us) ----------

__global__ __launch_bounds__(256) void proj_kernel(
    const float* __restrict__ agg,      // [NQ,128] mean
    const float* __restrict__ P0, const float* __restrict__ pb0,
    const float* __restrict__ P1, const float* __restrict__ pb1,
    float* __restrict__ out, int nq)
{
    int q = blockIdx.x * blockDim.x + threadIdx.x;
    if (q >= nq) return;

    float a[128];
    const float4* ag4 = (const float4*)(agg + (size_t)q * 128);
#pragma unroll
    for (int i = 0; i < 32; ++i) {
        float4 v = ag4[i];
        a[4 * i + 0] = v.x; a[4 * i + 1] = v.y;
        a[4 * i + 2] = v.z; a[4 * i + 3] = v.w;
    }

    float o0 = pb1[0], o1 = pb1[1], o2 = pb1[2], o3 = pb1[3];
#pragma unroll 1
    for (int jj = 0; jj < 256; jj += 8) {
        float acc[8];
#pragma unroll
        for (int u = 0; u < 8; ++u) acc[u] = pb0[jj + u];
#pragma unroll
        for (int i = 0; i < 128; ++i) {
            float av = a[i];
#pragma unroll
            for (int u = 0; u < 8; ++u)
                acc[u] = fmaf(av, P0[i * 256 + jj + u], acc[u]);
        }
#pragma unroll
        for (int u = 0; u < 8; ++u) {
            float h = gelu_f(acc[u]);
            o0 = fmaf(h, P1[(jj + u) * 4 + 0], o0);
            o1 = fmaf(h, P1[(jj + u) * 4 + 1], o1);
            o2 = fmaf(h, P1[(jj + u) * 4 + 2], o2);
            o3 = fmaf(h, P1[(jj + u) * 4 + 3], o3);
        }
    }
    float4* o4 = (float4*)(out + (size_t)q * 4);
    *o4 = make_float4(o0, o1, o2, o3);
}

extern "C" void kernel_launch(void* const* d_in, const int* in_sizes, int n_in,
                              void* d_out, int out_size, void* d_ws, size_t ws_size,
                              hipStream_t stream)
{
    const float* rndata = (const float*)d_in[0];
    const float* qpos   = (const float*)d_in[1];
    const float* lpos   = (const float*)d_in[2];
    const int*   dst    = (const int*)d_in[3];
    const int*   src    = (const int*)d_in[4];
    const float* W0  = (const float*)d_in[5];
    const float* b0  = (const float*)d_in[6];
    const float* W1  = (const float*)d_in[7];
    const float* b1  = (const float*)d_in[8];
    const float* W2  = (const float*)d_in[9];
    const float* b2  = (const float*)d_in[10];
    const float* P0  = (const float*)d_in[11];
    const float* pb0 = (const float*)d_in[12];
    const float* P1  = (const float*)d_in[13];
    const float* pb1 = (const float*)d_in[14];

    int nq = in_sizes[1] / 3;
    int E  = in_sizes[3];

    // ws layout: [agg nq*128 (path A)] [hist] [cursor] [start] [dsts] [srcs] [wimg]
    size_t agg_bytes  = (size_t)nq * 128 * sizeof(float);
    size_t sort_bytes = 0;
    {
        size_t o = 0;
        o += ((size_t)nq * sizeof(int) + 15) & ~(size_t)15;
        o += ((size_t)nq * sizeof(int) + 15) & ~(size_t)15;
        o += ((size_t)(nq + 1) * sizeof(int) + 15) & ~(size_t)15;
        o += ((size_t)E * sizeof(int) + 15) & ~(size_t)15;
        o += ((size_t)E * sizeof(int) + 15) & ~(size_t)15;
        o += 24576;  // packed f16 weight image
        sort_bytes = o;
    }
    bool path_a = (agg_bytes + sort_bytes) <= ws_size;

    size_t off = path_a ? agg_bytes : 0;
    auto alloc = [&](size_t bytes) {
        void* p = (char*)d_ws + off;
        off += (bytes + 15) & ~(size_t)15;
        return p;
    };
    float* agg   = (float*)d_ws;  // path A only
    int* hist    = (int*)alloc((size_t)nq * sizeof(int));
    int* cursor  = (int*)alloc((size_t)nq * sizeof(int));
    int* start   = (int*)alloc((size_t)(nq + 1) * sizeof(int));
    int* dsts    = (int*)alloc((size_t)E * sizeof(int));
    int* srcs    = (int*)alloc((size_t)E * sizeof(int));
    uint4* wimg  = (uint4*)alloc(24576);

    size_t histpad = ((size_t)nq * sizeof(int) + 15) & ~(size_t)15;
    hipMemsetAsync(hist, 0, 2 * histpad, stream);

    wprep_kernel<<<1, 256, 0, stream>>>(W1, W2, wimg);
    hist_kernel<<<(E + 255) / 256, 256, 0, stream>>>(dst, hist, E);
    scan_kernel<<<1, 1024, 0, stream>>>(hist, start, nq);
    scatter_kernel<<<(E + 255) / 256, 256, 0, stream>>>(dst, src, start, cursor, dsts, srcs, E);

    constexpr int    QB   = 12;
    constexpr size_t SMEM = 8192 + (size_t)QB * 129 * 4;  // 14,384 B (not limiting)
    int nb = (nq + QB - 1) / QB;

    if (path_a) {
        fused_kernel<QB, false><<<nb, BLOCK, SMEM, stream>>>(
            rndata, qpos, lpos, dsts, srcs, start,
            W0, b0, b1, b2, wimg, P0, pb0, P1, pb1, agg, nullptr, nq);
        proj_kernel<<<(nq + 255) / 256, 256, 0, stream>>>(
            agg, P0, pb0, P1, pb1, (float*)d_out, nq);
    } else {
        fused_kernel<QB, true><<<nb, BLOCK, SMEM, stream>>>(
            rndata, qpos, lpos, dsts, srcs, start,
            W0, b0, b1, b2, wimg, P0, pb0, P1, pb1, nullptr, (float*)d_out, nq);
    }
}

// Round 17
// 1167.708 us; speedup vs baseline: 1.1807x; 1.1807x over previous
//
#include <hip/hip_runtime.h>

// GNODecoder round 28: edge-record gather elimination.
// r27 post-mortem (REGRESSION 770->960): global B-loads re-inflated live
// ranges -> VGPR pinned at 128, WRITE 50->550MB (spills back), FETCH +480MB.
// Reverted. Key NEW fact: occupancy stuck at 22% in BOTH r26 (theoretical
// 50%) and r27 -> more-waves is not the lever; the per-tile serial gather
// chain (srcs[e] -> lpos[s], ~600-900cy) on a ~2000cy critical path is.
// r28 = r26 structure (LDS weights, proven 770us, no spills) + 32B edge
// records {d,s,qpos[d],lpos[s]} built in the scatter pass: fused tile head
// becomes ONE coalesced 32B load, zero dependent hops; epilogue d/s from
// the same L1-hot line. ws +24MB (84.4MB total) with templated fallback to
// the exact r26 path if it doesn't fit.
// Predicted: fused 770 -> 500-620us; FETCH ~190MB; WRITE ~50MB; VGPR<=126.

#define BLOCK 256

typedef _Float16 half8 __attribute__((ext_vector_type(8)));
typedef float f32x4 __attribute__((ext_vector_type(4)));

// LDS byte layout (fused kernel):
//   [0,     8192)  W1T : [64 n][64 k] f16, chunk ^= (n&7)
//   [8192, 24576)  W2T : [128 n][64 k] f16, same swizzle
//   [24576, 32768) hbuf: per-wave 2 KB, [16 rows][8 chunks of 16B], chunk^=(row&7)
//   [32768, ... )  sacc: [QB][129] f32

__device__ __forceinline__ float gelu_f(float x) {
    // jax.nn.gelu default (approximate=True, tanh form)
    float x3 = x * x * x;
    float t  = 0.7978845608028654f * fmaf(0.044715f, x3, x);
    float e  = __expf(2.0f * t);
    float r  = __builtin_amdgcn_rcpf(e + 1.0f);
    return 0.5f * x * (1.0f + (1.0f - 2.0f * r));
}

// ---------- sort machinery (proven) ----------

__global__ void hist_kernel(const int* __restrict__ dst, int* __restrict__ hist, int E) {
    int e = blockIdx.x * blockDim.x + threadIdx.x;
    if (e < E) atomicAdd(&hist[dst[e]], 1);
}

__global__ __launch_bounds__(1024) void scan_kernel(const int* __restrict__ hist,
                                                    int* __restrict__ start, int n) {
    __shared__ int wsum[16];
    __shared__ int woff[16];
    int tid = threadIdx.x;
    int lane = tid & 63, wid = tid >> 6;
    int carry = 0;  // meaningful on tid 0 only
    for (int base = 0; base < n; base += 1024) {
        int i = base + tid;
        int v = (i < n) ? hist[i] : 0;
        int incl = v;
#pragma unroll
        for (int off = 1; off < 64; off <<= 1) {
            int t = __shfl_up(incl, off, 64);
            if (lane >= off) incl += t;
        }
        if (lane == 63) wsum[wid] = incl;
        __syncthreads();
        if (tid == 0) {
            int acc = carry;
#pragma unroll
            for (int w = 0; w < 16; ++w) { woff[w] = acc; acc += wsum[w]; }
            carry = acc;
        }
        __syncthreads();
        if (i < n) start[i] = woff[wid] + incl - v;
        __syncthreads();
    }
    if (threadIdx.x == 0) start[n] = carry;
}

// old path: positions only
__global__ void scatter_kernel(const int* __restrict__ dst, const int* __restrict__ src,
                               const int* __restrict__ start, int* __restrict__ cursor,
                               int* __restrict__ dsts, int* __restrict__ srcs, int E) {
    int e = blockIdx.x * blockDim.x + threadIdx.x;
    if (e >= E) return;
    int d = dst[e];
    int pos = start[d] + atomicAdd(&cursor[d], 1);
    dsts[pos] = d;
    srcs[pos] = src[e];
}

// rec path: 32B record {d, s, qpos[d].xyz, lpos[s].xyz}
__global__ void scatter_rec_kernel(const int* __restrict__ dst, const int* __restrict__ src,
                                   const int* __restrict__ start, int* __restrict__ cursor,
                                   const float* __restrict__ qpos,
                                   const float* __restrict__ lpos,
                                   uint4* __restrict__ recs, int E) {
    int e = blockIdx.x * blockDim.x + threadIdx.x;
    if (e >= E) return;
    int d = dst[e], s = src[e];
    int pos = start[d] + atomicAdd(&cursor[d], 1);
    const float* pq = qpos + (size_t)d * 3;
    const float* pl = lpos + (size_t)s * 3;
    uint4 u0, u1;
    u0.x = (unsigned)d;            u0.y = (unsigned)s;
    u0.z = __float_as_uint(pq[0]); u0.w = __float_as_uint(pq[1]);
    u1.x = __float_as_uint(pq[2]); u1.y = __float_as_uint(pl[0]);
    u1.z = __float_as_uint(pl[1]); u1.w = __float_as_uint(pl[2]);
    size_t ri = (size_t)pos * 2;
    recs[ri] = u0; recs[ri + 1] = u1;
}

// ---------- weight prep: f16, transposed [n][k], XOR-swizzled image ----------
// img bytes: W1T at [0,8192), W2T at [8192,24576).
// element (n,k): byte = base + n*128 + (((k>>3) ^ (n&7))*16) + (k&7)*2

__global__ void wprep_kernel(const float* __restrict__ W1,
                             const float* __restrict__ W2,
                             char* __restrict__ img) {
    union { _Float16 h[8]; uint4 u; } cv;
    for (int task = threadIdx.x; task < 1536; task += 256) {
        bool isW2 = task >= 512;
        int id = isW2 ? task - 512 : task;
        int n = id >> 3, kc = id & 7;
        const float* W = isW2 ? W2 : W1;
        int N = isW2 ? 128 : 64;
#pragma unroll
        for (int j = 0; j < 8; ++j) cv.h[j] = (_Float16)W[(kc * 8 + j) * N + n];
        *(uint4*)(img + (isW2 ? 8192 : 0) + n * 128 + ((kc ^ (n & 7)) * 16)) = cv.u;
    }
}

// ---------- fused: wave-private 16-edge tiles, zero barriers in loop ----------

template <int QB, bool FUSED_PROJ, bool RECS>
__global__ __launch_bounds__(BLOCK, 2) void fused_kernel(
    const float* __restrict__ rndata,   // [NL,128]
    const float* __restrict__ qpos,     // [NQ,3]
    const float* __restrict__ lpos,     // [NL,3]
    const uint4* __restrict__ recs,     // [E*2] edge records (RECS path)
    const int*   __restrict__ dsts,     // [E] sorted by dst (old path)
    const int*   __restrict__ srcs,     // [E] (old path)
    const int*   __restrict__ start,    // [NQ+1]
    const float* __restrict__ W0, const float* __restrict__ b0,
    const float* __restrict__ b1, const float* __restrict__ b2,
    const uint4* __restrict__ wimg,     // 24576 B packed W1T/W2T image
    const float* __restrict__ P0, const float* __restrict__ pb0,
    const float* __restrict__ P1, const float* __restrict__ pb1,
    float* __restrict__ agg,            // [NQ,128] mean (path A)
    float* __restrict__ out,            // [NQ,4]   (FUSED_PROJ)
    int nq)
{
    extern __shared__ char smemc[];
    float* sacc = (float*)(smemc + 32768);
    const int tid = threadIdx.x;

    // stage weight image -> LDS [0, 24576)
    {
        uint4* wdst = (uint4*)smemc;
        for (int i = tid; i < 1536; i += BLOCK) wdst[i] = wimg[i];
    }
    for (int i = tid; i < QB * 129; i += BLOCK) sacc[i] = 0.f;

    const int q0   = blockIdx.x * QB;
    const int qend = min(q0 + QB, nq);
    const int e0 = start[q0], e1 = start[qend];
    const int ntl = (e1 - e0 + 15) >> 4;   // 16-edge tiles

    const int m   = tid & 63;
    const int wid = tid >> 6;
    const int c16 = m & 15;
    const int g   = m >> 4;                // 0..3 = k-group

    char* hb = smemc + 24576 + wid * 2048; // wave-private h1 buffer
    const int aoff0 = c16 * 128 + (((0 + g) ^ (c16 & 7)) * 16);  // A frag k=g*8..
    const int aoff1 = c16 * 128 + (((4 + g) ^ (c16 & 7)) * 16);  // A frag k=32+g*8..

    // per-lane bias slices (hoisted; 12 loop-carried regs)
    float b1v[4], b2v[8];
#pragma unroll
    for (int nt = 0; nt < 4; ++nt) b1v[nt] = b1[nt * 16 + c16];
#pragma unroll
    for (int nt = 0; nt < 8; ++nt) b2v[nt] = b2[nt * 16 + c16];

    __syncthreads();  // weights staged + sacc zeroed (only barrier before tail)

    for (int t = wid; t < ntl; t += 4) {
        const int eb = e0 + (t << 4);

        float pin[6];
        int s_ep[4], soff[4];
        bool v_ep[4];

        if constexpr (RECS) {
            // ---- ONE coalesced 32B record load; zero dependent hops ----
            const int  eA = eb + c16;
            const bool vA = eA < e1;
            size_t ri = (size_t)(vA ? eA : e0) * 2;
            uint4 ra = recs[ri];
            uint4 rb = recs[ri + 1];
            pin[0] = __uint_as_float(ra.z); pin[1] = __uint_as_float(ra.w);
            pin[2] = __uint_as_float(rb.x); pin[3] = __uint_as_float(rb.y);
            pin[4] = __uint_as_float(rb.z); pin[5] = __uint_as_float(rb.w);
            // epilogue d/s pairs: 8B loads from the same L1-hot 512B line
#pragma unroll
            for (int i = 0; i < 4; ++i) {
                int ee  = eb + g * 4 + i;
                v_ep[i] = ee < e1;
                uint2 ds = *(const uint2*)&recs[(size_t)(v_ep[i] ? ee : e0) * 2];
                s_ep[i] = (int)ds.y;
                soff[i] = ((int)ds.x - q0) * 129 + c16;
            }
        } else {
            // ---- old r26 path: index gather + dependent pos gather ----
            const int  eA = eb + c16;
            const bool vA = eA < e1;
            const int  dA = vA ? dsts[eA] : q0;
            const int  sA = vA ? srcs[eA] : 0;
#pragma unroll
            for (int i = 0; i < 4; ++i) {
                int ee = eb + g * 4 + i;
                v_ep[i] = ee < e1;
                int d   = v_ep[i] ? dsts[ee] : q0;
                s_ep[i] = v_ep[i] ? srcs[ee] : 0;
                soff[i] = (d - q0) * 129 + c16;
            }
            const float* pq = qpos + dA * 3;
            pin[0] = pq[0]; pin[1] = pq[1]; pin[2] = pq[2];
            const float* pl = lpos + sA * 3;
            pin[3] = pl[0]; pin[4] = pl[1]; pin[5] = pl[2];
        }

        // ---- L0: compute A-fragment directly (edge c16, cols g*8 sliced) ----
        float C0[16];
        {
            const float* b0p = b0 + g * 8;
            *(float4*)&C0[0]  = *(const float4*)(b0p);
            *(float4*)&C0[4]  = *(const float4*)(b0p + 4);
            *(float4*)&C0[8]  = *(const float4*)(b0p + 32);
            *(float4*)&C0[12] = *(const float4*)(b0p + 36);
        }
#pragma unroll
        for (int k = 0; k < 6; ++k) {
            const float a  = pin[k];
            const float* w = W0 + k * 64 + g * 8;   // L1-hot (1.5 KB total)
            float wv[16];
            *(float4*)&wv[0]  = *(const float4*)(w);
            *(float4*)&wv[4]  = *(const float4*)(w + 4);
            *(float4*)&wv[8]  = *(const float4*)(w + 32);
            *(float4*)&wv[12] = *(const float4*)(w + 36);
#pragma unroll
            for (int j = 0; j < 16; ++j) C0[j] = fmaf(a, wv[j], C0[j]);
        }
        union { _Float16 h[8]; half8 v; } u0, u1;
#pragma unroll
        for (int j = 0; j < 8; ++j) u0.h[j] = (_Float16)gelu_f(C0[j]);
#pragma unroll
        for (int j = 0; j < 8; ++j) u1.h[j] = (_Float16)gelu_f(C0[8 + j]);
        const half8 a0 = u0.v, a1 = u1.v;   // h0 A-fragments: no LDS round-trip

        // ---- GEMM2 interleaved with h1 transpose (c1 = one transient f32x4) ----
#pragma unroll
        for (int nt = 0; nt < 4; ++nt) {
            const int  nrow = nt * 16 + c16;
            const char* wb  = smemc + nrow * 128;
            half8 bb0 = *(const half8*)(wb + (((0 + g) ^ (nrow & 7)) * 16));
            half8 bb1 = *(const half8*)(wb + (((4 + g) ^ (nrow & 7)) * 16));
            f32x4 acc = {b1v[nt], b1v[nt], b1v[nt], b1v[nt]};
            acc = __builtin_amdgcn_mfma_f32_16x16x32_f16(a0, bb0, acc, 0, 0, 0);
            acc = __builtin_amdgcn_mfma_f32_16x16x32_f16(a1, bb1, acc, 0, 0, 0);
#pragma unroll
            for (int i = 0; i < 4; ++i) {
                const int row  = g * 4 + i;
                const int colh = nt * 16 + c16;
                *(_Float16*)(hb + row * 128 + (((colh >> 3) ^ (row & 7)) * 16)
                             + (colh & 7) * 2) = (_Float16)gelu_f(acc[i]);
            }
        }
        // in-order DS per wave: reads below see the 16 writes above
        const half8 a2 = *(const half8*)(hb + aoff0);
        const half8 a3 = *(const half8*)(hb + aoff1);

        // ---- GEMM3 + epilogue, 2-deep rolling rndata buffer ----
        f32x4 rAv, rBv;
#pragma unroll
        for (int i = 0; i < 4; ++i)
            rAv[i] = rndata[(size_t)s_ep[i] * 128 + c16];      // nt=0 column
#pragma unroll
        for (int nt = 0; nt < 8; ++nt) {
            if (nt < 7) {        // issue nt+1 loads (hide under MFMAs)
                if (nt & 1) {
#pragma unroll
                    for (int i = 0; i < 4; ++i)
                        rAv[i] = rndata[(size_t)s_ep[i] * 128 + (nt + 1) * 16 + c16];
                } else {
#pragma unroll
                    for (int i = 0; i < 4; ++i)
                        rBv[i] = rndata[(size_t)s_ep[i] * 128 + (nt + 1) * 16 + c16];
                }
            }
            const int  nrow = nt * 16 + c16;
            const char* wb  = smemc + 8192 + nrow * 128;
            half8 bb0 = *(const half8*)(wb + (((0 + g) ^ (nrow & 7)) * 16));
            half8 bb1 = *(const half8*)(wb + (((4 + g) ^ (nrow & 7)) * 16));
            f32x4 acc = {b2v[nt], b2v[nt], b2v[nt], b2v[nt]};
            acc = __builtin_amdgcn_mfma_f32_16x16x32_f16(a2, bb0, acc, 0, 0, 0);
            acc = __builtin_amdgcn_mfma_f32_16x16x32_f16(a3, bb1, acc, 0, 0, 0);
#pragma unroll
            for (int i = 0; i < 4; ++i) {
                float rc = (nt & 1) ? rBv[i] : rAv[i];
                if (v_ep[i]) atomicAdd(&sacc[soff[i] + nt * 16], acc[i] * rc);
            }
        }
    }
    __syncthreads();  // all waves' ds_adds visible

    if (!FUSED_PROJ) {
        for (int idx = tid; idx < QB * 128; idx += BLOCK) {
            int ql = idx >> 7, c = idx & 127;
            int q  = q0 + ql;
            if (q < qend) {
                float deg = (float)(start[q + 1] - start[q]);
                agg[(size_t)q * 128 + c] = sacc[ql * 129 + c] / fmaxf(deg, 1.f);
            }
        }
    } else {
        if (tid < QB) {
            int q = q0 + tid;
            if (q < nq) {
                float deg = (float)(start[q + 1] - start[q]);
                float inv = 1.0f / fmaxf(deg, 1.f);
                const float* aq = &sacc[tid * 129];
                float o0 = pb1[0], o1 = pb1[1], o2 = pb1[2], o3 = pb1[3];
#pragma unroll 1
                for (int jj = 0; jj < 256; jj += 8) {
                    float acc[8];
#pragma unroll
                    for (int u = 0; u < 8; ++u) acc[u] = pb0[jj + u];
#pragma unroll
                    for (int i = 0; i < 128; ++i) {
                        float av = aq[i] * inv;
#pragma unroll
                        for (int u = 0; u < 8; ++u)
                            acc[u] = fmaf(av, P0[i * 256 + jj + u], acc[u]);
                    }
#pragma unroll
                    for (int u = 0; u < 8; ++u) {
                        float h = gelu_f(acc[u]);
                        o0 = fmaf(h, P1[(jj + u) * 4 + 0], o0);
                        o1 = fmaf(h, P1[(jj + u) * 4 + 1], o1);
                        o2 = fmaf(h, P1[(jj + u) * 4 + 2], o2);
                        o3 = fmaf(h, P1[(jj + u) * 4 + 3], o3);
                    }
                }
                float4* o4 = (float4*)(out + (size_t)q * 4);
                *o4 = make_float4(o0, o1, o2, o3);
            }
        }
    }
}

// ---------- projection: plain r7/r9 kernel (proven ~270 us) ----------

__global__ __launch_bounds__(256) void proj_kernel(
    const float* __restrict__ agg,      // [NQ,128] mean
    const float* __restrict__ P0, const float* __restrict__ pb0,
    const float* __restrict__ P1, const float* __restrict__ pb1,
    float* __restrict__ out, int nq)
{
    int q = blockIdx.x * blockDim.x + threadIdx.x;
    if (q >= nq) return;

    float a[128];
    const float4* ag4 = (const float4*)(agg + (size_t)q * 128);
#pragma unroll
    for (int i = 0; i < 32; ++i) {
        float4 v = ag4[i];
        a[4 * i + 0] = v.x; a[4 * i + 1] = v.y;
        a[4 * i + 2] = v.z; a[4 * i + 3] = v.w;
    }

    float o0 = pb1[0], o1 = pb1[1], o2 = pb1[2], o3 = pb1[3];
#pragma unroll 1
    for (int jj = 0; jj < 256; jj += 8) {
        float acc[8];
#pragma unroll
        for (int u = 0; u < 8; ++u) acc[u] = pb0[jj + u];
#pragma unroll
        for (int i = 0; i < 128; ++i) {
            float av = a[i];
#pragma unroll
            for (int u = 0; u < 8; ++u)
                acc[u] = fmaf(av, P0[i * 256 + jj + u], acc[u]);
        }
#pragma unroll
        for (int u = 0; u < 8; ++u) {
            float h = gelu_f(acc[u]);
            o0 = fmaf(h, P1[(jj + u) * 4 + 0], o0);
            o1 = fmaf(h, P1[(jj + u) * 4 + 1], o1);
            o2 = fmaf(h, P1[(jj + u) * 4 + 2], o2);
            o3 = fmaf(h, P1[(jj + u) * 4 + 3], o3);
        }
    }
    float4* o4 = (float4*)(out + (size_t)q * 4);
    *o4 = make_float4(o0, o1, o2, o3);
}

extern "C" void kernel_launch(void* const* d_in, const int* in_sizes, int n_in,
                              void* d_out, int out_size, void* d_ws, size_t ws_size,
                              hipStream_t stream)
{
    const float* rndata = (const float*)d_in[0];
    const float* qpos   = (const float*)d_in[1];
    const float* lpos   = (const float*)d_in[2];
    const int*   dst    = (const int*)d_in[3];
    const int*   src    = (const int*)d_in[4];
    const float* W0  = (const float*)d_in[5];
    const float* b0  = (const float*)d_in[6];
    const float* W1  = (const float*)d_in[7];
    const float* b1  = (const float*)d_in[8];
    const float* W2  = (const float*)d_in[9];
    const float* b2  = (const float*)d_in[10];
    const float* P0  = (const float*)d_in[11];
    const float* pb0 = (const float*)d_in[12];
    const float* P1  = (const float*)d_in[13];
    const float* pb1 = (const float*)d_in[14];

    int nq = in_sizes[1] / 3;
    int E  = in_sizes[3];

    size_t agg_bytes  = (size_t)nq * 128 * sizeof(float);
    size_t histpad    = ((size_t)nq * sizeof(int) + 15) & ~(size_t)15;
    size_t startpad   = ((size_t)(nq + 1) * sizeof(int) + 15) & ~(size_t)15;
    size_t epad       = ((size_t)E * sizeof(int) + 15) & ~(size_t)15;
    size_t recs_bytes = (size_t)E * 32;
    size_t fixed      = 2 * histpad + startpad;

    size_t need_rec = agg_bytes + fixed + recs_bytes + 24576;   // rec path + agg
    size_t need_old = agg_bytes + fixed + 2 * epad + 24576;     // old path + agg

    bool use_rec = ws_size >= need_rec;
    bool path_a  = use_rec || (ws_size >= need_old);

    size_t off = path_a ? agg_bytes : 0;
    auto alloc = [&](size_t bytes) {
        void* p = (char*)d_ws + off;
        off += (bytes + 15) & ~(size_t)15;
        return p;
    };
    float* agg   = (float*)d_ws;  // path A only
    int* hist    = (int*)alloc((size_t)nq * sizeof(int));
    int* cursor  = (int*)alloc((size_t)nq * sizeof(int));
    int* start   = (int*)alloc((size_t)(nq + 1) * sizeof(int));
    uint4* recs  = nullptr;
    int* dsts    = nullptr;
    int* srcs    = nullptr;
    if (use_rec) {
        recs = (uint4*)alloc(recs_bytes);
    } else {
        dsts = (int*)alloc((size_t)E * sizeof(int));
        srcs = (int*)alloc((size_t)E * sizeof(int));
    }
    uint4* wimg  = (uint4*)alloc(24576);

    hipMemsetAsync(hist, 0, 2 * histpad, stream);

    wprep_kernel<<<1, 256, 0, stream>>>(W1, W2, (char*)wimg);
    hist_kernel<<<(E + 255) / 256, 256, 0, stream>>>(dst, hist, E);
    scan_kernel<<<1, 1024, 0, stream>>>(hist, start, nq);
    if (use_rec) {
        scatter_rec_kernel<<<(E + 255) / 256, 256, 0, stream>>>(
            dst, src, start, cursor, qpos, lpos, recs, E);
    } else {
        scatter_kernel<<<(E + 255) / 256, 256, 0, stream>>>(
            dst, src, start, cursor, dsts, srcs, E);
    }

    constexpr int    QB   = 12;
    constexpr size_t SMEM = 32768 + (size_t)QB * 129 * 4;  // 38,960 B -> 4 blocks/CU
    int nb = (nq + QB - 1) / QB;

    if (path_a) {
        if (use_rec) {
            fused_kernel<QB, false, true><<<nb, BLOCK, SMEM, stream>>>(
                rndata, qpos, lpos, recs, dsts, srcs, start,
                W0, b0, b1, b2, wimg, P0, pb0, P1, pb1, agg, nullptr, nq);
        } else {
            fused_kernel<QB, false, false><<<nb, BLOCK, SMEM, stream>>>(
                rndata, qpos, lpos, recs, dsts, srcs, start,
                W0, b0, b1, b2, wimg, P0, pb0, P1, pb1, agg, nullptr, nq);
        }
        proj_kernel<<<(nq + 255) / 256, 256, 0, stream>>>(
            agg, P0, pb0, P1, pb1, (float*)d_out, nq);
    } else {
        fused_kernel<QB, true, false><<<nb, BLOCK, SMEM, stream>>>(
            rndata, qpos, lpos, recs, dsts, srcs, start,
            W0, b0, b1, b2, wimg, P0, pb0, P1, pb1, nullptr, (float*)d_out, nq);
    }
}